// Round 1
// baseline (86.970 us; speedup 1.0000x reference)
//
#include <hip/hip_runtime.h>

// loss = -(1/B) * sum_{b,c} preds_t[b,c] * log(preds_s[b,c])
// B=4096, C=1000, fp32 in, fp32 scalar out. Memory-bound: 32.77 MB read
// (~5.5 us at 6.3 TB/s). Harness re-poisons the 256 MiB workspace inside
// the timed window (~44 us fillBuffer per iteration, rocprof-verified) —
// that part is untouchable. R3: fuse the two-kernel reduction into ONE
// dispatch with a lock-free flag protocol to remove kernel2's dispatch
// gap (~2 us kernel + ~4-6 us graph gap).
//
// Protocol: each block plain-computes its partial, release-stores
// {partial, MAGIC flag} at agent scope into d_ws. Block 0 acquire-spins
// on all 1024 flags, then reduces and writes out[0] (full overwrite of
// poisoned d_out — no memset dispatch). Flags need no init: poison !=
// MAGIC (a collision would fail verification deterministically, so a
// passing run validates the assumption). No deadlock: only block 0
// waits; every other block runs to completion unconditionally.

#define BLOCK 256
#define GRID1 1024            // 4 waves/block * 1024 = 4096 waves; HBM-saturating
#define FLAG_MAGIC 0x5bd1e995u

__global__ __launch_bounds__(BLOCK) void kd_fused_kernel(
    const float* __restrict__ preds_s,
    const float* __restrict__ preds_t,
    float* __restrict__ ws,        // d_ws: [0,GRID1) partials, [GRID1,2*GRID1) flags
    float* __restrict__ out,
    int n,                         // total elements (B*C)
    float scale)                   // -1/B
{
    float* partials = ws;
    unsigned int* flags = (unsigned int*)(ws + GRID1);

    const int n4 = n >> 2;
    const float4* s4 = (const float4*)preds_s;
    const float4* t4 = (const float4*)preds_t;

    float acc = 0.0f;
    for (int i = blockIdx.x * BLOCK + threadIdx.x; i < n4;
         i += GRID1 * BLOCK) {
        float4 a = s4[i];
        float4 b = t4[i];
        acc += b.x * __logf(a.x);
        acc += b.y * __logf(a.y);
        acc += b.z * __logf(a.z);
        acc += b.w * __logf(a.w);
    }

    // scalar tail (n % 4 != 0), block 0 only; empty for n = 4,096,000
    if (blockIdx.x == 0) {
        for (int i = (n4 << 2) + threadIdx.x; i < n; i += BLOCK)
            acc += preds_t[i] * __logf(preds_s[i]);
    }

    // wave-64 butterfly reduce
    #pragma unroll
    for (int off = 32; off > 0; off >>= 1)
        acc += __shfl_down(acc, off, 64);

    __shared__ float wsum[BLOCK / 64];
    const int lane = threadIdx.x & 63;
    const int wid  = threadIdx.x >> 6;
    if (lane == 0) wsum[wid] = acc;
    __syncthreads();

    if (threadIdx.x == 0) {
        float r = wsum[0] + wsum[1] + wsum[2] + wsum[3];
        // partial first (relaxed), then flag with RELEASE at agent scope:
        // orders the partial store before the flag store, visible cross-XCD.
        __hip_atomic_store(&partials[blockIdx.x], r,
                           __ATOMIC_RELAXED, __HIP_MEMORY_SCOPE_AGENT);
        __hip_atomic_store(&flags[blockIdx.x], FLAG_MAGIC,
                           __ATOMIC_RELEASE, __HIP_MEMORY_SCOPE_AGENT);
    }

    // Block 0 performs the final reduction in the same dispatch.
    if (blockIdx.x == 0) {
        float local = 0.0f;
        for (int j = threadIdx.x; j < GRID1; j += BLOCK) {   // 4 flags/thread
            while (__hip_atomic_load(&flags[j], __ATOMIC_ACQUIRE,
                                     __HIP_MEMORY_SCOPE_AGENT) != FLAG_MAGIC) {
                __builtin_amdgcn_s_sleep(1);
            }
            // acquire above orders this read after the producer's release
            local += __hip_atomic_load(&partials[j], __ATOMIC_RELAXED,
                                       __HIP_MEMORY_SCOPE_AGENT);
        }

        #pragma unroll
        for (int off = 32; off > 0; off >>= 1)
            local += __shfl_down(local, off, 64);

        __syncthreads();               // wsum reuse: ensure phase-1 reads done
        if (lane == 0) wsum[wid] = local;
        __syncthreads();

        if (threadIdx.x == 0)
            out[0] = (wsum[0] + wsum[1] + wsum[2] + wsum[3]) * scale;
    }
}

extern "C" void kernel_launch(void* const* d_in, const int* in_sizes, int n_in,
                              void* d_out, int out_size, void* d_ws, size_t ws_size,
                              hipStream_t stream) {
    const float* preds_s = (const float*)d_in[0];
    const float* preds_t = (const float*)d_in[1];
    float* out = (float*)d_out;
    float* ws  = (float*)d_ws;          // 8 KB used << ws_size

    const int n = in_sizes[0];          // B*C = 4096*1000
    const int B = 4096;                 // fixed by the problem
    const float scale = -1.0f / (float)B;

    kd_fused_kernel<<<GRID1, BLOCK, 0, stream>>>(preds_s, preds_t, ws, out, n, scale);
}

// Round 2
// 74.898 us; speedup vs baseline: 1.1612x; 1.1612x over previous
//
#include <hip/hip_runtime.h>

// loss = -(1/B) * sum_{b,c} preds_t[b,c] * log(preds_s[b,c])
// B=4096, C=1000, fp32 in, fp32 scalar out. Memory-bound: 32.77 MB read
// (~5.5 us at achievable 6.3 TB/s).
//
// R4 = revert to R2 (harness-verified 74.3 us). Per-iteration budget,
// rocprof-derived: 43.5 us unconditional 256 MiB ws-poison fill (76-78%
// HBM peak, harness-side) + ~20 us fixed graph-replay overhead
// (invariant to dispatch count: R1 memset+kernel = 75.0 ~= R2 two
// kernels = 74.3) + ~5.5 us mandatory input read + ~3 us reduce tail.
// R3's single-dispatch flag-spin protocol cost +14 us of kernel time
// (agent-scope acquire spin = per-load L1 invalidation, serialized
// after the slowest block) for a <=2 us theoretical saving — reverted.
//
// Structure: atomic-free two-kernel reduction. Kernel1 -> d_ws partials
// (plain stores over poison), kernel2 reduces partials and writes the
// scaled result (fully overwrites poisoned d_out — no memset needed).

#define BLOCK 256
#define GRID1 1024   // 4 blocks/CU; 16 waves/CU — enough to saturate HBM

__global__ __launch_bounds__(BLOCK) void kd_partial_kernel(
    const float* __restrict__ preds_s,
    const float* __restrict__ preds_t,
    float* __restrict__ partials,   // d_ws, GRID1 floats
    int n)                          // total elements (B*C)
{
    const int n4 = n >> 2;
    const float4* s4 = (const float4*)preds_s;
    const float4* t4 = (const float4*)preds_t;

    float acc = 0.0f;
    for (int i = blockIdx.x * BLOCK + threadIdx.x; i < n4;
         i += GRID1 * BLOCK) {
        float4 a = s4[i];
        float4 b = t4[i];
        acc += b.x * __logf(a.x);
        acc += b.y * __logf(a.y);
        acc += b.z * __logf(a.z);
        acc += b.w * __logf(a.w);
    }

    // scalar tail (n % 4 != 0), block 0 only; empty for n = 4,096,000
    if (blockIdx.x == 0) {
        for (int i = (n4 << 2) + threadIdx.x; i < n; i += BLOCK)
            acc += preds_t[i] * __logf(preds_s[i]);
    }

    // wave-64 butterfly reduce
    #pragma unroll
    for (int off = 32; off > 0; off >>= 1)
        acc += __shfl_down(acc, off, 64);

    __shared__ float wsum[BLOCK / 64];
    const int lane = threadIdx.x & 63;
    const int wid  = threadIdx.x >> 6;
    if (lane == 0) wsum[wid] = acc;
    __syncthreads();

    if (threadIdx.x == 0) {
        float r = 0.0f;
        #pragma unroll
        for (int w = 0; w < BLOCK / 64; ++w) r += wsum[w];
        partials[blockIdx.x] = r;    // plain store — no init required
    }
}

__global__ __launch_bounds__(BLOCK) void kd_final_kernel(
    const float* __restrict__ partials,  // GRID1 floats
    float* __restrict__ out,
    float scale)                         // -1/B
{
    // GRID1 = 1024 partials = 256 threads x float4
    const float4* p4 = (const float4*)partials;
    float4 v = p4[threadIdx.x];
    float acc = v.x + v.y + v.z + v.w;

    #pragma unroll
    for (int off = 32; off > 0; off >>= 1)
        acc += __shfl_down(acc, off, 64);

    __shared__ float wsum[BLOCK / 64];
    const int lane = threadIdx.x & 63;
    const int wid  = threadIdx.x >> 6;
    if (lane == 0) wsum[wid] = acc;
    __syncthreads();

    if (threadIdx.x == 0) {
        float r = 0.0f;
        #pragma unroll
        for (int w = 0; w < BLOCK / 64; ++w) r += wsum[w];
        out[0] = r * scale;   // fully overwrites d_out — no memset needed
    }
}

extern "C" void kernel_launch(void* const* d_in, const int* in_sizes, int n_in,
                              void* d_out, int out_size, void* d_ws, size_t ws_size,
                              hipStream_t stream) {
    const float* preds_s = (const float*)d_in[0];
    const float* preds_t = (const float*)d_in[1];
    float* out = (float*)d_out;
    float* partials = (float*)d_ws;     // 4 KB used << ws_size

    const int n = in_sizes[0];          // B*C = 4096*1000
    const int B = 4096;                 // fixed by the problem
    const float scale = -1.0f / (float)B;

    kd_partial_kernel<<<GRID1, BLOCK, 0, stream>>>(preds_s, preds_t, partials, n);
    kd_final_kernel<<<1, BLOCK, 0, stream>>>(partials, out, scale);
}